// Round 1
// baseline (677.281 us; speedup 1.0000x reference)
//
#include <hip/hip_runtime.h>
#include <math.h>

#define N 8192
#define D 256
#define EPSF 1e-6f

#define BM 128
#define BN 128
#define BK 16

// ---------------- Kernel 1: Q row sums (Sq), zero wsum ----------------
__global__ __launch_bounds__(256) void qrowsum_kernel(const float* __restrict__ Q,
                                                      float* __restrict__ Sq,
                                                      float* __restrict__ wsum) {
    int row = blockIdx.x;
    const float4* q4 = (const float4*)(Q + (size_t)row * N);
    float s = 0.f;
    for (int k = threadIdx.x; k < N / 4; k += 256) {
        float4 v = q4[k];
        s += v.x + v.y + v.z + v.w;
    }
    __shared__ float red[4];
    for (int off = 32; off > 0; off >>= 1) s += __shfl_down(s, off, 64);
    if ((threadIdx.x & 63) == 0) red[threadIdx.x >> 6] = s;
    __syncthreads();
    if (threadIdx.x == 0) {
        Sq[row] = red[0] + red[1] + red[2] + red[3];
        wsum[row] = 0.f;
    }
}

// ---------------- Kernel 2: zW = z @ W  [N,D]x[D,D] ----------------
__global__ __launch_bounds__(256) void zw_kernel(const float* __restrict__ z,
                                                 const float* __restrict__ W,
                                                 float* __restrict__ zW) {
    __shared__ float zs[32 * D];  // 32 rows of z, 32 KB
    int rowBase = blockIdx.x * 32;
    const float4* zg = (const float4*)(z + (size_t)rowBase * D);
    float4* zs4 = (float4*)zs;
    for (int i = threadIdx.x; i < 32 * D / 4; i += 256) zs4[i] = zg[i];
    __syncthreads();

    float acc[32];
#pragma unroll
    for (int r = 0; r < 32; ++r) acc[r] = 0.f;
    int col = threadIdx.x;
    for (int kb = 0; kb < D; kb += 4) {
        float w0 = W[(size_t)(kb + 0) * D + col];
        float w1 = W[(size_t)(kb + 1) * D + col];
        float w2 = W[(size_t)(kb + 2) * D + col];
        float w3 = W[(size_t)(kb + 3) * D + col];
#pragma unroll
        for (int r = 0; r < 32; ++r) {
            float4 zv = *(const float4*)&zs[r * D + kb];
            acc[r] = fmaf(zv.x, w0, acc[r]);
            acc[r] = fmaf(zv.y, w1, acc[r]);
            acc[r] = fmaf(zv.z, w2, acc[r]);
            acc[r] = fmaf(zv.w, w3, acc[r]);
        }
    }
#pragma unroll
    for (int r = 0; r < 32; ++r) zW[(size_t)(rowBase + r) * D + col] = acc[r];
}

// ---------------- Kernel 3: sim = zW @ z^T, fused elementwise + rowsum ----------------
// Each block: 128x128 output tile, 256 threads, 8x8 per thread.
// Thread (tx,ty), tx=t&15, ty=t>>4. Rows: ty*8+r. Cols: tx*4+c (c<4), 64+tx*4+(c-4).
__global__ __launch_bounds__(256) void sim_fuse_kernel(const float* __restrict__ A,   // zW [N,D]
                                                       const float* __restrict__ Bz,  // z  [N,D]
                                                       const float* __restrict__ beta,
                                                       const float* __restrict__ Q,
                                                       const float* __restrict__ Sq,
                                                       float* __restrict__ out,
                                                       float* __restrict__ wsum) {
    __shared__ float As[BK][BM];
    __shared__ float Bs[BK][BN];
    int rowBase = blockIdx.y * BM;
    int colBase = blockIdx.x * BN;
    int t = threadIdx.x;
    int tx = t & 15, ty = t >> 4;

    float acc[8][8];
#pragma unroll
    for (int r = 0; r < 8; ++r)
#pragma unroll
        for (int c = 0; c < 8; ++c) acc[r][c] = 0.f;

    for (int kt = 0; kt < D; kt += BK) {
        // stage 128x16 of A and B (transposed into LDS): 512 float4 each, 2 per thread
#pragma unroll
        for (int u = 0; u < 2; ++u) {
            int f = t + u * 256;      // 0..511
            int row = f >> 2;         // 0..127
            int cg = f & 3;           // which float4 along K
            float4 av = *(const float4*)&A[(size_t)(rowBase + row) * D + kt + cg * 4];
            float4 bv = *(const float4*)&Bz[(size_t)(colBase + row) * D + kt + cg * 4];
            As[cg * 4 + 0][row] = av.x;
            As[cg * 4 + 1][row] = av.y;
            As[cg * 4 + 2][row] = av.z;
            As[cg * 4 + 3][row] = av.w;
            Bs[cg * 4 + 0][row] = bv.x;
            Bs[cg * 4 + 1][row] = bv.y;
            Bs[cg * 4 + 2][row] = bv.z;
            Bs[cg * 4 + 3][row] = bv.w;
        }
        __syncthreads();
#pragma unroll
        for (int kk = 0; kk < BK; ++kk) {
            float4 a0 = *(const float4*)&As[kk][ty * 8];
            float4 a1 = *(const float4*)&As[kk][ty * 8 + 4];
            float4 b0 = *(const float4*)&Bs[kk][tx * 4];
            float4 b1 = *(const float4*)&Bs[kk][64 + tx * 4];
            float a[8] = {a0.x, a0.y, a0.z, a0.w, a1.x, a1.y, a1.z, a1.w};
            float b[8] = {b0.x, b0.y, b0.z, b0.w, b1.x, b1.y, b1.z, b1.w};
#pragma unroll
            for (int r = 0; r < 8; ++r)
#pragma unroll
                for (int c = 0; c < 8; ++c) acc[r][c] = fmaf(a[r], b[c], acc[r][c]);
        }
        __syncthreads();
    }

    // epilogue: v = sqrt(relu(sim-beta)+eps) * (0.5 + 0.5*Q/Sq); write v; rowsum partials
#pragma unroll
    for (int r = 0; r < 8; ++r) {
        int i = rowBase + ty * 8 + r;
        float bi = beta[i];
        float inv2s = 0.5f / Sq[i];
        const float* qrow = Q + (size_t)i * N + colBase;
        float* orow = out + (size_t)i * N + colBase;

        float4 q0 = *(const float4*)&qrow[tx * 4];
        float4 q1 = *(const float4*)&qrow[64 + tx * 4];
        float qv[8] = {q0.x, q0.y, q0.z, q0.w, q1.x, q1.y, q1.z, q1.w};
        float v[8];
        float rsum = 0.f;
#pragma unroll
        for (int c = 0; c < 8; ++c) {
            float x = fmaxf(acc[r][c] - bi, 0.f) + EPSF;
            float a = sqrtf(x);
            float w = a * (0.5f + qv[c] * inv2s);
            v[c] = w;
            rsum += w;
        }
        *(float4*)&orow[tx * 4] = make_float4(v[0], v[1], v[2], v[3]);
        *(float4*)&orow[64 + tx * 4] = make_float4(v[4], v[5], v[6], v[7]);

        rsum += __shfl_xor(rsum, 1, 64);
        rsum += __shfl_xor(rsum, 2, 64);
        rsum += __shfl_xor(rsum, 4, 64);
        rsum += __shfl_xor(rsum, 8, 64);
        if (tx == 0) atomicAdd(&wsum[i], rsum);
    }
}

// ---------------- Kernel 4: row-normalize ----------------
__global__ __launch_bounds__(256) void norm_kernel(float* __restrict__ out,
                                                   const float* __restrict__ wsum) {
    int row = blockIdx.x;
    float inv = 1.0f / wsum[row];
    float4* o4 = (float4*)(out + (size_t)row * N);
    for (int k = threadIdx.x; k < N / 4; k += 256) {
        float4 v = o4[k];
        v.x *= inv;
        v.y *= inv;
        v.z *= inv;
        v.w *= inv;
        o4[k] = v;
    }
}

extern "C" void kernel_launch(void* const* d_in, const int* in_sizes, int n_in,
                              void* d_out, int out_size, void* d_ws, size_t ws_size,
                              hipStream_t stream) {
    const float* z = (const float*)d_in[0];
    const float* W = (const float*)d_in[1];
    const float* beta = (const float*)d_in[2];
    const float* Q = (const float*)d_in[3];
    float* out = (float*)d_out;

    float* Sq = (float*)d_ws;           // N floats
    float* wsum = Sq + N;               // N floats
    float* zW = wsum + N;               // N*D floats

    qrowsum_kernel<<<N, 256, 0, stream>>>(Q, Sq, wsum);
    zw_kernel<<<N / 32, 256, 0, stream>>>(z, W, zW);
    dim3 g3(N / BN, N / BM);
    sim_fuse_kernel<<<g3, 256, 0, stream>>>(zW, z, beta, Q, Sq, out, wsum);
    norm_kernel<<<N, 256, 0, stream>>>(out, wsum);
}